// Round 4
// baseline (620.893 us; speedup 1.0000x reference)
//
#include <hip/hip_runtime.h>

typedef __attribute__((ext_vector_type(8))) short short8v;
typedef __attribute__((ext_vector_type(4))) float f32x4;
typedef __attribute__((ext_vector_type(4))) unsigned int uint4v;

#define GLOBAL_AS(p) ((const __attribute__((address_space(1))) void*)(p))
#define LDS_AS(p)    ((__attribute__((address_space(3))) void*)(p))
#define WAITV(n) asm volatile("s_waitcnt vmcnt(" #n ")" ::: "memory")
#define LGKM0()  asm volatile("s_waitcnt lgkmcnt(0)" ::: "memory")
#define BARRIER() __builtin_amdgcn_s_barrier()
#define SCHED0() __builtin_amdgcn_sched_barrier(0)

__device__ __forceinline__ unsigned short f2bf(float f) {
  unsigned int u = __builtin_bit_cast(unsigned int, f);
  u += 0x7fffu + ((u >> 16) & 1u);
  return (unsigned short)(u >> 16);
}
__device__ __forceinline__ float bf2f(unsigned short u) {
  unsigned int x = ((unsigned int)u) << 16;
  return __builtin_bit_cast(float, x);
}

// ---------------------------------------------------------------------------
// Transpose fp32 [K,N] -> bf16 [N,K]
__global__ __launch_bounds__(256) void transpose_to_bf16(
    const float* __restrict__ src, unsigned short* __restrict__ dst,
    int K, int N, int ntx) {
  __shared__ float tile[32][33];
  const int bx = blockIdx.x % ntx;
  const int by = blockIdx.x / ntx;
  const int tx = threadIdx.x & 31, ty = threadIdx.x >> 5;
  const int k0 = by * 32, n0 = bx * 32;
#pragma unroll
  for (int i = 0; i < 32; i += 8)
    tile[ty + i][tx] = src[(size_t)(k0 + ty + i) * N + n0 + tx];
  __syncthreads();
#pragma unroll
  for (int i = 0; i < 32; i += 8)
    dst[(size_t)(n0 + ty + i) * K + k0 + tx] = f2bf(tile[tx][ty + i]);
}

// fp32 -> bf16, 8 elements/thread
__global__ __launch_bounds__(256) void cvt_f32_bf16(
    const float* __restrict__ s, unsigned short* __restrict__ d) {
  size_t i = ((size_t)blockIdx.x * 256 + threadIdx.x) * 8;
  f32x4 v0 = *(const f32x4*)(s + i);
  f32x4 v1 = *(const f32x4*)(s + i + 4);
  union U8 { uint4v v; unsigned short us[8]; } o;
  o.us[0] = f2bf(v0.x); o.us[1] = f2bf(v0.y); o.us[2] = f2bf(v0.z); o.us[3] = f2bf(v0.w);
  o.us[4] = f2bf(v1.x); o.us[5] = f2bf(v1.y); o.us[6] = f2bf(v1.z); o.us[7] = f2bf(v1.w);
  *(uint4v*)(d + i) = o.v;
}

// combined bias concat: b1 = [bd_k|bd_v|bq] (3072), b2 = [bu_k|bu_v] (4096)
__global__ __launch_bounds__(256) void fill_bias(
    const float* __restrict__ bd_k, const float* __restrict__ bd_v,
    const float* __restrict__ bq, const float* __restrict__ bu_k,
    const float* __restrict__ bu_v, float* __restrict__ b1, float* __restrict__ b2) {
  int i = blockIdx.x * 256 + threadIdx.x;
  if (i < 512) b1[i] = bd_k[i];
  else if (i < 1024) b1[i] = bd_v[i - 512];
  else if (i < 3072) b1[i] = bq[i - 1024];
  else if (i < 5120) b2[i - 3072] = bu_k[i - 3072];
  else if (i < 7168) b2[i - 3072] = bu_v[i - 5120];
}

// ---------------------------------------------------------------------------
// 256x256x64 bf16 GEMM, 8 waves (2Mx4N), per-wave 128x64.
// 8-phase schedule: per K-tile 4 phases {miLO/miHI x ks0/ks1}, each phase =
// 8 ds_read_b128 + staged prefetch + barrier + lgkmcnt(0) + 16 MFMA + barrier.
// Stage unit = 64 rows x 64 cols (one 512-thread global_load_lds issue).
// Stage schedule (derived, slot-conflict-free, 6-phase lead):
//   p1: A(T+1)Q1,Q3 + B(T+1)q0,q1   (dbuf^1; freed at end of tile T-1)
//   p2: B(T+1)q2,q3
//   p3: A(T+2)Q0,Q2                 (dbuf;   freed after p2 of tile T)
//   p4: -, then s_waitcnt vmcnt(2)  (only p3's 2 issues stay in flight)
template <int OUT_BF16>
__global__ __launch_bounds__(512, 2) void gemm_bt(
    const unsigned short* __restrict__ A, int lda, int nsplit_col, int acol_off,
    const unsigned short* __restrict__ Bt, int ldb,
    const float* __restrict__ bias, void* __restrict__ Cp, int ldc,
    int K, int ntn) {
  __shared__ unsigned short lds[2][2][256 * 64];  // [dbuf][A|B][row*64+col]
  const int t = threadIdx.x;
  const int lane = t & 63, wave = t >> 6;

  // bijective XCD swizzle (grids here are multiples of 8)
  const int qx = gridDim.x >> 3;
  const int bid = (blockIdx.x & 7) * qx + (blockIdx.x >> 3);
  const int bm = (bid / ntn) * 256;
  const int bn = (bid % ntn) * 256;
  const unsigned short* Ab = A + (bn >= nsplit_col ? acol_off : 0);

  const int wr = wave >> 2, wc = wave & 3;
  const int g = lane >> 4, r = lane & 15;
  const int swz = r & 7;
  const int NT = K >> 6;

  f32x4 acc[8][4];
#pragma unroll
  for (int i = 0; i < 8; ++i)
#pragma unroll
    for (int j = 0; j < 4; ++j) acc[i][j] = (f32x4){0.f, 0.f, 0.f, 0.f};

  // staging geometry: one issue = 64 rows x 64 cols; thread t -> row t>>3,
  // source chunk inverse-XOR-swizzled so linear LDS + swizzled read match.
  const int trow = t >> 3;
  const int jsrc = (t & 7) ^ (trow & 7);
  const unsigned short* aptr = Ab + (size_t)(bm + trow) * lda + (jsrc << 3);
  const unsigned short* bptr = Bt + (size_t)(bn + trow) * ldb + (jsrc << 3);
  const int wbase = wave * 512;

  auto stageA = [&](int kt, int buf, int q64) {
    __builtin_amdgcn_global_load_lds(
        GLOBAL_AS(aptr + (size_t)(q64 * 64) * lda + kt * 64),
        LDS_AS(&lds[buf][0][q64 * 4096 + wbase]), 16, 0, 0);
  };
  auto stageB = [&](int kt, int buf, int q64) {
    __builtin_amdgcn_global_load_lds(
        GLOBAL_AS(bptr + (size_t)(q64 * 64) * ldb + kt * 64),
        LDS_AS(&lds[buf][1][q64 * 4096 + wbase]), 16, 0, 0);
  };

  auto phaseReads = [&](const unsigned short* la, const unsigned short* lb,
                        int miH, int ks, short8v (&af)[4], short8v (&bf)[4]) {
    const int c16 = (((ks << 2) + g) ^ swz) << 3;
#pragma unroll
    for (int mi = 0; mi < 4; ++mi)
      af[mi] = *(const short8v*)&la[(wr * 128 + miH * 64 + mi * 16 + r) * 64 + c16];
#pragma unroll
    for (int ni = 0; ni < 4; ++ni)
      bf[ni] = *(const short8v*)&lb[(wc * 64 + ni * 16 + r) * 64 + c16];
  };
  auto phaseMfma = [&](int miH, short8v (&af)[4], short8v (&bf)[4]) {
    __builtin_amdgcn_s_setprio(1);
#pragma unroll
    for (int mi = 0; mi < 4; ++mi)
#pragma unroll
      for (int ni = 0; ni < 4; ++ni)
        acc[miH * 4 + mi][ni] = __builtin_amdgcn_mfma_f32_16x16x32_bf16(
            af[mi], bf[ni], acc[miH * 4 + mi][ni], 0, 0, 0);
    __builtin_amdgcn_s_setprio(0);
  };

  // prologue: tile0 (8 issues) + A(1)Q0,Q2 (2 issues); keep last 2 in flight
  stageA(0, 0, 0); stageA(0, 0, 1); stageA(0, 0, 2); stageA(0, 0, 3);
  stageB(0, 0, 0); stageB(0, 0, 1); stageB(0, 0, 2); stageB(0, 0, 3);
  if (NT > 1) { stageA(1, 1, 0); stageA(1, 1, 2); }
  WAITV(2);
  BARRIER();

  for (int T = 0; T < NT; ++T) {
    const int cur = T & 1, nxt = cur ^ 1;
    const unsigned short* la = lds[cur][0];
    const unsigned short* lb = lds[cur][1];
    const bool s1 = (T + 1 < NT), s2 = (T + 2 < NT);
    short8v af[4], bf[4];

    // ---- p1: miLO x ks0
    SCHED0();
    phaseReads(la, lb, 0, 0, af, bf);
    SCHED0();
    if (s1) {
      stageA(T + 1, nxt, 1); stageA(T + 1, nxt, 3);
      stageB(T + 1, nxt, 0); stageB(T + 1, nxt, 1);
    }
    SCHED0();
    BARRIER();
    LGKM0(); SCHED0();
    phaseMfma(0, af, bf);
    SCHED0();
    BARRIER();

    // ---- p2: miLO x ks1
    SCHED0();
    phaseReads(la, lb, 0, 1, af, bf);
    SCHED0();
    if (s1) { stageB(T + 1, nxt, 2); stageB(T + 1, nxt, 3); }
    SCHED0();
    BARRIER();
    LGKM0(); SCHED0();
    phaseMfma(0, af, bf);
    SCHED0();
    BARRIER();

    // ---- p3: miHI x ks0
    SCHED0();
    phaseReads(la, lb, 1, 0, af, bf);
    SCHED0();
    if (s2) { stageA(T + 2, cur, 0); stageA(T + 2, cur, 2); }
    SCHED0();
    BARRIER();
    LGKM0(); SCHED0();
    phaseMfma(1, af, bf);
    SCHED0();
    BARRIER();

    // ---- p4: miHI x ks1
    SCHED0();
    phaseReads(la, lb, 1, 1, af, bf);
    SCHED0();
    BARRIER();
    LGKM0(); SCHED0();
    phaseMfma(1, af, bf);
    SCHED0();
    if (s2) { WAITV(2); } else { WAITV(0); }
    BARRIER();
  }

#pragma unroll
  for (int ni = 0; ni < 4; ++ni) {
    const int col = bn + wc * 64 + ni * 16 + r;
    const float bv = bias[col];
#pragma unroll
    for (int mi = 0; mi < 8; ++mi) {
      const int row0 = bm + wr * 128 + mi * 16 + (g << 2);
#pragma unroll
      for (int j = 0; j < 4; ++j) {
        float v = acc[mi][ni][j] + bv;
        if (OUT_BF16)
          ((unsigned short*)Cp)[(size_t)(row0 + j) * ldc + col] = f2bf(v);
        else
          ((float*)Cp)[(size_t)(row0 + j) * ldc + col] = v;
      }
    }
  }
}

// ---------------------------------------------------------------------------
// Per-token head-vs-head attention (16x16 per token), fp32 math.
__global__ __launch_bounds__(256) void attn_kernel(
    const unsigned short* __restrict__ out1, const unsigned short* __restrict__ kv,
    unsigned short* __restrict__ aout) {
  const int s = blockIdx.x;
  const int t = threadIdx.x;
  __shared__ float qs[16 * 132], ks2[16 * 132], vs[16 * 132];
  __shared__ float attn[256];
  const int h = t >> 4, d0 = (t & 15) * 8;

  union U8 { uint4v v; unsigned short us[8]; };
  U8 qv, kv8, vv;
  qv.v = *(const uint4v*)(out1 + (size_t)s * 3072 + 1024 + t * 8);
  kv8.v = *(const uint4v*)(kv + (size_t)s * 4096 + t * 8);
  vv.v = *(const uint4v*)(kv + (size_t)s * 4096 + 2048 + t * 8);
#pragma unroll
  for (int j = 0; j < 8; ++j) {
    qs[h * 132 + d0 + j] = bf2f(qv.us[j]);
    ks2[h * 132 + d0 + j] = bf2f(kv8.us[j]);
    vs[h * 132 + d0 + j] = bf2f(vv.us[j]);
  }
  __syncthreads();

  const int gg0 = t & 15;
  const f32x4* qrow = (const f32x4*)&qs[h * 132];
  const f32x4* krow = (const f32x4*)&ks2[gg0 * 132];
  float acc = 0.f;
#pragma unroll
  for (int dd = 0; dd < 32; ++dd) {
    f32x4 a4 = qrow[dd], b4 = krow[dd];
    acc += a4.x * b4.x + a4.y * b4.y + a4.z * b4.z + a4.w * b4.w;
  }
  acc *= 0.08838834764831845f;
  float mx = acc;
#pragma unroll
  for (int o = 8; o; o >>= 1) mx = fmaxf(mx, __shfl_xor(mx, o));
  float e = __expf(acc - mx);
  float sm = e;
#pragma unroll
  for (int o = 8; o; o >>= 1) sm += __shfl_xor(sm, o);
  attn[t] = e / sm;
  __syncthreads();

  f32x4 o0 = (f32x4){0.f, 0.f, 0.f, 0.f}, o1 = (f32x4){0.f, 0.f, 0.f, 0.f};
#pragma unroll
  for (int gg = 0; gg < 16; ++gg) {
    const float a = attn[(h << 4) + gg];
    f32x4 v0 = *(const f32x4*)&vs[gg * 132 + d0];
    f32x4 v1 = *(const f32x4*)&vs[gg * 132 + d0 + 4];
    o0 += v0 * a;
    o1 += v1 * a;
  }
  U8 ov;
  ov.us[0] = f2bf(o0.x); ov.us[1] = f2bf(o0.y); ov.us[2] = f2bf(o0.z); ov.us[3] = f2bf(o0.w);
  ov.us[4] = f2bf(o1.x); ov.us[5] = f2bf(o1.y); ov.us[6] = f2bf(o1.z); ov.us[7] = f2bf(o1.w);
  *(uint4v*)(aout + (size_t)s * 2048 + t * 8) = ov.v;
}

// ---------------------------------------------------------------------------
extern "C" void kernel_launch(void* const* d_in, const int* in_sizes, int n_in,
                              void* d_out, int out_size, void* d_ws, size_t ws_size,
                              hipStream_t stream) {
  (void)in_sizes; (void)n_in; (void)out_size; (void)ws_size;
  const float* x    = (const float*)d_in[0];
  const float* Wd_k = (const float*)d_in[1];
  const float* bd_k = (const float*)d_in[2];
  const float* Wu_k = (const float*)d_in[3];
  const float* bu_k = (const float*)d_in[4];
  const float* Wd_v = (const float*)d_in[5];
  const float* bd_v = (const float*)d_in[6];
  const float* Wu_v = (const float*)d_in[7];
  const float* bu_v = (const float*)d_in[8];
  const float* Wq   = (const float*)d_in[9];
  const float* bq   = (const float*)d_in[10];
  const float* Wo   = (const float*)d_in[11];
  const float* bo   = (const float*)d_in[12];

  char* ws = (char*)d_ws;
  unsigned short* w1t  = (unsigned short*)(ws);             // [3072][2048] bf16
  unsigned short* w2t  = (unsigned short*)(ws + 12582912);  // [4096][512]  bf16
  unsigned short* w3t  = (unsigned short*)(ws + 16777216);  // [2048][2048] bf16
  float*          b1   = (float*)(ws + 25165824);           // [3072]
  float*          b2   = (float*)(ws + 25178112);           // [4096]
  unsigned short* xb   = (unsigned short*)(ws + 25194496);  // [16384][2048] bf16
  unsigned short* out1 = (unsigned short*)(ws + 92303360);  // [16384][3072] bf16
  unsigned short* kvb  = (unsigned short*)(ws + 192966656); // [16384][4096] bf16
  unsigned short* attO = xb;  // reuse xb after GEMM1

  dim3 blk(256);

  transpose_to_bf16<<<dim3(16 * 64), blk, 0, stream>>>(Wd_k, w1t,               2048, 512, 16);
  transpose_to_bf16<<<dim3(16 * 64), blk, 0, stream>>>(Wd_v, w1t + 512 * 2048,  2048, 512, 16);
  transpose_to_bf16<<<dim3(64 * 64), blk, 0, stream>>>(Wq,   w1t + 1024 * 2048, 2048, 2048, 64);
  transpose_to_bf16<<<dim3(64 * 16), blk, 0, stream>>>(Wu_k, w2t,               512, 2048, 64);
  transpose_to_bf16<<<dim3(64 * 16), blk, 0, stream>>>(Wu_v, w2t + 2048 * 512,  512, 2048, 64);
  transpose_to_bf16<<<dim3(64 * 64), blk, 0, stream>>>(Wo,   w3t,               2048, 2048, 64);

  fill_bias<<<dim3(28), blk, 0, stream>>>(bd_k, bd_v, bq, bu_k, bu_v, b1, b2);

  cvt_f32_bf16<<<dim3(16384), blk, 0, stream>>>(x, xb);

  // GEMM1: [16384,2048]@[2048,3072] -> out1 (cache_k|cache_v|q)
  gemm_bt<1><<<dim3(64 * 12), dim3(512), 0, stream>>>(
      xb, 2048, 1 << 30, 0, w1t, 2048, b1, out1, 3072, 2048, 12);

  // GEMM2 fused: k|v = [cache_k|cache_v]@blockdiag(Wu_k,Wu_v) -> kvb
  gemm_bt<1><<<dim3(64 * 16), dim3(512), 0, stream>>>(
      out1, 3072, 2048, 512, w2t, 512, b2, kvb, 4096, 512, 16);

  // per-token attention
  attn_kernel<<<dim3(16384), blk, 0, stream>>>(out1, kvb, attO);

  // GEMM3: attO@Wo + bo -> d_out fp32
  gemm_bt<0><<<dim3(64 * 8), dim3(512), 0, stream>>>(
      attO, 2048, 1 << 30, 0, w3t, 2048, bo, (float*)d_out, 2048, 2048, 8);
}

// Round 5
// 611.983 us; speedup vs baseline: 1.0146x; 1.0146x over previous
//
#include <hip/hip_runtime.h>

typedef __attribute__((ext_vector_type(8))) short short8v;
typedef __attribute__((ext_vector_type(4))) float f32x4;
typedef __attribute__((ext_vector_type(4))) unsigned int uint4v;

#define GLOBAL_AS(p) ((const __attribute__((address_space(1))) void*)(p))
#define LDS_AS(p)    ((__attribute__((address_space(3))) void*)(p))
#define WAITV(n) asm volatile("s_waitcnt vmcnt(" #n ")" ::: "memory")
#define LGKM0()  asm volatile("s_waitcnt lgkmcnt(0)" ::: "memory")
#define BARRIER() __builtin_amdgcn_s_barrier()
#define SCHED0() __builtin_amdgcn_sched_barrier(0)

__device__ __forceinline__ unsigned short f2bf(float f) {
  unsigned int u = __builtin_bit_cast(unsigned int, f);
  u += 0x7fffu + ((u >> 16) & 1u);
  return (unsigned short)(u >> 16);
}
__device__ __forceinline__ float bf2f(unsigned short u) {
  unsigned int x = ((unsigned int)u) << 16;
  return __builtin_bit_cast(float, x);
}

// ---------------------------------------------------------------------------
// Transpose fp32 [K,N] -> bf16 [N,K]
__global__ __launch_bounds__(256) void transpose_to_bf16(
    const float* __restrict__ src, unsigned short* __restrict__ dst,
    int K, int N, int ntx) {
  __shared__ float tile[32][33];
  const int bx = blockIdx.x % ntx;
  const int by = blockIdx.x / ntx;
  const int tx = threadIdx.x & 31, ty = threadIdx.x >> 5;
  const int k0 = by * 32, n0 = bx * 32;
#pragma unroll
  for (int i = 0; i < 32; i += 8)
    tile[ty + i][tx] = src[(size_t)(k0 + ty + i) * N + n0 + tx];
  __syncthreads();
#pragma unroll
  for (int i = 0; i < 32; i += 8)
    dst[(size_t)(n0 + ty + i) * K + k0 + tx] = f2bf(tile[tx][ty + i]);
}

// fp32 -> bf16, 8 elements/thread
__global__ __launch_bounds__(256) void cvt_f32_bf16(
    const float* __restrict__ s, unsigned short* __restrict__ d) {
  size_t i = ((size_t)blockIdx.x * 256 + threadIdx.x) * 8;
  f32x4 v0 = *(const f32x4*)(s + i);
  f32x4 v1 = *(const f32x4*)(s + i + 4);
  union U8 { uint4v v; unsigned short us[8]; } o;
  o.us[0] = f2bf(v0.x); o.us[1] = f2bf(v0.y); o.us[2] = f2bf(v0.z); o.us[3] = f2bf(v0.w);
  o.us[4] = f2bf(v1.x); o.us[5] = f2bf(v1.y); o.us[6] = f2bf(v1.z); o.us[7] = f2bf(v1.w);
  *(uint4v*)(d + i) = o.v;
}

// combined bias concat: b1 = [bd_k|bd_v|bq] (3072), b2 = [bu_k|bu_v] (4096)
__global__ __launch_bounds__(256) void fill_bias(
    const float* __restrict__ bd_k, const float* __restrict__ bd_v,
    const float* __restrict__ bq, const float* __restrict__ bu_k,
    const float* __restrict__ bu_v, float* __restrict__ b1, float* __restrict__ b2) {
  int i = blockIdx.x * 256 + threadIdx.x;
  if (i < 512) b1[i] = bd_k[i];
  else if (i < 1024) b1[i] = bd_v[i - 512];
  else if (i < 3072) b1[i] = bq[i - 1024];
  else if (i < 5120) b2[i - 3072] = bu_k[i - 3072];
  else if (i < 7168) b2[i - 3072] = bu_v[i - 5120];
}

// ---------------------------------------------------------------------------
// 256x256x64 bf16 GEMM, 8 waves (2Mx4N), per-wave 128x64.
// 8-phase schedule, minimal fencing (SCHED0 only after LGKM0, rule 18).
// Phases per K-tile T: p1(miLO,ks0) p2(miLO,ks1) p3(miHI,ks0) p4(miHI,ks1).
// Stage 2 issues/phase into dbuf^1, all for tile T+1:
//   p1: A Q0,Q2 (needed next-p1; 3-phase lead, A streams from HBM)
//   p2: B q0,q1 | p3: B q2,q3 (weights, L2-hot, short lead OK)
//   p4: A Q1,Q3 (needed next-p3; 4-phase lead)
// Waits (per-wave vmcnt bookkeeping, steady state 8 outstanding at p4-end):
//   p2-end: vmcnt(4) drains prior tile's A Q1,Q3 before p3 reads them
//           (vmcnt(0) on last tile: no new issues pad the count)
//   p4-end: vmcnt(2) drains the 6 issues next-p1 needs, keeps A Q1,Q3 flying
template <int OUT_BF16>
__global__ __launch_bounds__(512, 2) void gemm_bt(
    const unsigned short* __restrict__ A, int lda, int nsplit_col, int acol_off,
    const unsigned short* __restrict__ Bt, int ldb,
    const float* __restrict__ bias, void* __restrict__ Cp, int ldc,
    int K, int ntn) {
  __shared__ unsigned short lds[2][2][256 * 64];  // [dbuf][A|B][row*64+col]
  const int t = threadIdx.x;
  const int lane = t & 63, wave = t >> 6;

  // bijective XCD swizzle (grids here are multiples of 8)
  const int qx = gridDim.x >> 3;
  const int bid = (blockIdx.x & 7) * qx + (blockIdx.x >> 3);
  const int bm = (bid / ntn) * 256;
  const int bn = (bid % ntn) * 256;
  const unsigned short* Ab = A + (bn >= nsplit_col ? acol_off : 0);

  const int wr = wave >> 2, wc = wave & 3;
  const int g = lane >> 4, r = lane & 15;
  const int swz = r & 7;
  const int NT = K >> 6;

  f32x4 acc[8][4];
#pragma unroll
  for (int i = 0; i < 8; ++i)
#pragma unroll
    for (int j = 0; j < 4; ++j) acc[i][j] = (f32x4){0.f, 0.f, 0.f, 0.f};

  // staging geometry: one issue = 64 rows x 64 cols; thread t -> row t>>3,
  // source chunk inverse-XOR-swizzled so linear LDS + swizzled read match.
  const int trow = t >> 3;
  const int jsrc = (t & 7) ^ (trow & 7);
  const unsigned short* aptr = Ab + (size_t)(bm + trow) * lda + (jsrc << 3);
  const unsigned short* bptr = Bt + (size_t)(bn + trow) * ldb + (jsrc << 3);
  const int wbase = wave * 512;

  auto stageA = [&](int kt, int buf, int q64) {
    __builtin_amdgcn_global_load_lds(
        GLOBAL_AS(aptr + (size_t)(q64 * 64) * lda + kt * 64),
        LDS_AS(&lds[buf][0][q64 * 4096 + wbase]), 16, 0, 0);
  };
  auto stageB = [&](int kt, int buf, int q64) {
    __builtin_amdgcn_global_load_lds(
        GLOBAL_AS(bptr + (size_t)(q64 * 64) * ldb + kt * 64),
        LDS_AS(&lds[buf][1][q64 * 4096 + wbase]), 16, 0, 0);
  };

  auto phaseReads = [&](const unsigned short* la, const unsigned short* lb,
                        int miH, int ks, short8v (&af)[4], short8v (&bf)[4]) {
    const int c16 = (((ks << 2) + g) ^ swz) << 3;
#pragma unroll
    for (int mi = 0; mi < 4; ++mi)
      af[mi] = *(const short8v*)&la[(wr * 128 + miH * 64 + mi * 16 + r) * 64 + c16];
#pragma unroll
    for (int ni = 0; ni < 4; ++ni)
      bf[ni] = *(const short8v*)&lb[(wc * 64 + ni * 16 + r) * 64 + c16];
  };
  auto phaseMfma = [&](int miH, short8v (&af)[4], short8v (&bf)[4]) {
    __builtin_amdgcn_s_setprio(1);
#pragma unroll
    for (int mi = 0; mi < 4; ++mi)
#pragma unroll
      for (int ni = 0; ni < 4; ++ni)
        acc[miH * 4 + mi][ni] = __builtin_amdgcn_mfma_f32_16x16x32_bf16(
            af[mi], bf[ni], acc[miH * 4 + mi][ni], 0, 0, 0);
    __builtin_amdgcn_s_setprio(0);
  };

  // prologue: stage tile0 fully, drain, align
  stageA(0, 0, 0); stageA(0, 0, 1); stageA(0, 0, 2); stageA(0, 0, 3);
  stageB(0, 0, 0); stageB(0, 0, 1); stageB(0, 0, 2); stageB(0, 0, 3);
  WAITV(0);
  BARRIER();

  for (int T = 0; T < NT; ++T) {
    const int cur = T & 1, nxt = cur ^ 1;
    const unsigned short* la = lds[cur][0];
    const unsigned short* lb = lds[cur][1];
    const bool s1 = (T + 1 < NT);
    short8v af[4], bf[4];

    // ---- p1: miLO x ks0  | stage A(T+1) Q0,Q2
    phaseReads(la, lb, 0, 0, af, bf);
    if (s1) { stageA(T + 1, nxt, 0); stageA(T + 1, nxt, 2); }
    BARRIER();
    LGKM0(); SCHED0();
    phaseMfma(0, af, bf);
    BARRIER();

    // ---- p2: miLO x ks1  | stage B(T+1) q0,q1
    phaseReads(la, lb, 0, 1, af, bf);
    if (s1) { stageB(T + 1, nxt, 0); stageB(T + 1, nxt, 1); }
    BARRIER();
    LGKM0(); SCHED0();
    phaseMfma(0, af, bf);
    if (s1) { WAITV(4); } else { WAITV(0); }
    BARRIER();

    // ---- p3: miHI x ks0  | stage B(T+1) q2,q3
    phaseReads(la, lb, 1, 0, af, bf);
    if (s1) { stageB(T + 1, nxt, 2); stageB(T + 1, nxt, 3); }
    BARRIER();
    LGKM0(); SCHED0();
    phaseMfma(1, af, bf);
    BARRIER();

    // ---- p4: miHI x ks1  | stage A(T+1) Q1,Q3
    phaseReads(la, lb, 1, 1, af, bf);
    if (s1) { stageA(T + 1, nxt, 1); stageA(T + 1, nxt, 3); }
    BARRIER();
    LGKM0(); SCHED0();
    phaseMfma(1, af, bf);
    if (s1) { WAITV(2); }
    BARRIER();
  }

#pragma unroll
  for (int ni = 0; ni < 4; ++ni) {
    const int col = bn + wc * 64 + ni * 16 + r;
    const float bv = bias[col];
#pragma unroll
    for (int mi = 0; mi < 8; ++mi) {
      const int row0 = bm + wr * 128 + mi * 16 + (g << 2);
#pragma unroll
      for (int j = 0; j < 4; ++j) {
        float v = acc[mi][ni][j] + bv;
        if (OUT_BF16)
          ((unsigned short*)Cp)[(size_t)(row0 + j) * ldc + col] = f2bf(v);
        else
          ((float*)Cp)[(size_t)(row0 + j) * ldc + col] = v;
      }
    }
  }
}

// ---------------------------------------------------------------------------
// Per-token head-vs-head attention (16x16 per token), fp32 math.
__global__ __launch_bounds__(256) void attn_kernel(
    const unsigned short* __restrict__ out1, const unsigned short* __restrict__ kv,
    unsigned short* __restrict__ aout) {
  const int s = blockIdx.x;
  const int t = threadIdx.x;
  __shared__ float qs[16 * 132], ks2[16 * 132], vs[16 * 132];
  __shared__ float attn[256];
  const int h = t >> 4, d0 = (t & 15) * 8;

  union U8 { uint4v v; unsigned short us[8]; };
  U8 qv, kv8, vv;
  qv.v = *(const uint4v*)(out1 + (size_t)s * 3072 + 1024 + t * 8);
  kv8.v = *(const uint4v*)(kv + (size_t)s * 4096 + t * 8);
  vv.v = *(const uint4v*)(kv + (size_t)s * 4096 + 2048 + t * 8);
#pragma unroll
  for (int j = 0; j < 8; ++j) {
    qs[h * 132 + d0 + j] = bf2f(qv.us[j]);
    ks2[h * 132 + d0 + j] = bf2f(kv8.us[j]);
    vs[h * 132 + d0 + j] = bf2f(vv.us[j]);
  }
  __syncthreads();

  const int gg0 = t & 15;
  const f32x4* qrow = (const f32x4*)&qs[h * 132];
  const f32x4* krow = (const f32x4*)&ks2[gg0 * 132];
  float acc = 0.f;
#pragma unroll
  for (int dd = 0; dd < 32; ++dd) {
    f32x4 a4 = qrow[dd], b4 = krow[dd];
    acc += a4.x * b4.x + a4.y * b4.y + a4.z * b4.z + a4.w * b4.w;
  }
  acc *= 0.08838834764831845f;
  float mx = acc;
#pragma unroll
  for (int o = 8; o; o >>= 1) mx = fmaxf(mx, __shfl_xor(mx, o));
  float e = __expf(acc - mx);
  float sm = e;
#pragma unroll
  for (int o = 8; o; o >>= 1) sm += __shfl_xor(sm, o);
  attn[t] = e / sm;
  __syncthreads();

  f32x4 o0 = (f32x4){0.f, 0.f, 0.f, 0.f}, o1 = (f32x4){0.f, 0.f, 0.f, 0.f};
#pragma unroll
  for (int gg = 0; gg < 16; ++gg) {
    const float a = attn[(h << 4) + gg];
    f32x4 v0 = *(const f32x4*)&vs[gg * 132 + d0];
    f32x4 v1 = *(const f32x4*)&vs[gg * 132 + d0 + 4];
    o0 += v0 * a;
    o1 += v1 * a;
  }
  U8 ov;
  ov.us[0] = f2bf(o0.x); ov.us[1] = f2bf(o0.y); ov.us[2] = f2bf(o0.z); ov.us[3] = f2bf(o0.w);
  ov.us[4] = f2bf(o1.x); ov.us[5] = f2bf(o1.y); ov.us[6] = f2bf(o1.z); ov.us[7] = f2bf(o1.w);
  *(uint4v*)(aout + (size_t)s * 2048 + t * 8) = ov.v;
}

// ---------------------------------------------------------------------------
extern "C" void kernel_launch(void* const* d_in, const int* in_sizes, int n_in,
                              void* d_out, int out_size, void* d_ws, size_t ws_size,
                              hipStream_t stream) {
  (void)in_sizes; (void)n_in; (void)out_size; (void)ws_size;
  const float* x    = (const float*)d_in[0];
  const float* Wd_k = (const float*)d_in[1];
  const float* bd_k = (const float*)d_in[2];
  const float* Wu_k = (const float*)d_in[3];
  const float* bu_k = (const float*)d_in[4];
  const float* Wd_v = (const float*)d_in[5];
  const float* bd_v = (const float*)d_in[6];
  const float* Wu_v = (const float*)d_in[7];
  const float* bu_v = (const float*)d_in[8];
  const float* Wq   = (const float*)d_in[9];
  const float* bq   = (const float*)d_in[10];
  const float* Wo   = (const float*)d_in[11];
  const float* bo   = (const float*)d_in[12];

  char* ws = (char*)d_ws;
  unsigned short* w1t  = (unsigned short*)(ws);             // [3072][2048] bf16
  unsigned short* w2t  = (unsigned short*)(ws + 12582912);  // [4096][512]  bf16
  unsigned short* w3t  = (unsigned short*)(ws + 16777216);  // [2048][2048] bf16
  float*          b1   = (float*)(ws + 25165824);           // [3072]
  float*          b2   = (float*)(ws + 25178112);           // [4096]
  unsigned short* xb   = (unsigned short*)(ws + 25194496);  // [16384][2048] bf16
  unsigned short* out1 = (unsigned short*)(ws + 92303360);  // [16384][3072] bf16
  unsigned short* kvb  = (unsigned short*)(ws + 192966656); // [16384][4096] bf16
  unsigned short* attO = xb;  // reuse xb after GEMM1

  dim3 blk(256);

  transpose_to_bf16<<<dim3(16 * 64), blk, 0, stream>>>(Wd_k, w1t,               2048, 512, 16);
  transpose_to_bf16<<<dim3(16 * 64), blk, 0, stream>>>(Wd_v, w1t + 512 * 2048,  2048, 512, 16);
  transpose_to_bf16<<<dim3(64 * 64), blk, 0, stream>>>(Wq,   w1t + 1024 * 2048, 2048, 2048, 64);
  transpose_to_bf16<<<dim3(64 * 16), blk, 0, stream>>>(Wu_k, w2t,               512, 2048, 64);
  transpose_to_bf16<<<dim3(64 * 16), blk, 0, stream>>>(Wu_v, w2t + 2048 * 512,  512, 2048, 64);
  transpose_to_bf16<<<dim3(64 * 64), blk, 0, stream>>>(Wo,   w3t,               2048, 2048, 64);

  fill_bias<<<dim3(28), blk, 0, stream>>>(bd_k, bd_v, bq, bu_k, bu_v, b1, b2);

  cvt_f32_bf16<<<dim3(16384), blk, 0, stream>>>(x, xb);

  // GEMM1: [16384,2048]@[2048,3072] -> out1 (cache_k|cache_v|q)
  gemm_bt<1><<<dim3(64 * 12), dim3(512), 0, stream>>>(
      xb, 2048, 1 << 30, 0, w1t, 2048, b1, out1, 3072, 2048, 12);

  // GEMM2 fused: k|v = [cache_k|cache_v]@blockdiag(Wu_k,Wu_v) -> kvb
  gemm_bt<1><<<dim3(64 * 16), dim3(512), 0, stream>>>(
      out1, 3072, 2048, 512, w2t, 512, b2, kvb, 4096, 512, 16);

  // per-token attention
  attn_kernel<<<dim3(16384), blk, 0, stream>>>(out1, kvb, attO);

  // GEMM3: attO@Wo + bo -> d_out fp32
  gemm_bt<0><<<dim3(64 * 8), dim3(512), 0, stream>>>(
      attO, 2048, 1 << 30, 0, w3t, 2048, bo, (float*)d_out, 2048, 2048, 8);
}

// Round 6
// 608.897 us; speedup vs baseline: 1.0197x; 1.0051x over previous
//
#include <hip/hip_runtime.h>

typedef __attribute__((ext_vector_type(8))) short short8v;
typedef __attribute__((ext_vector_type(4))) float f32x4;
typedef __attribute__((ext_vector_type(16))) float f32x16;
typedef __attribute__((ext_vector_type(4))) unsigned int uint4v;

#define GLOBAL_AS(p) ((const __attribute__((address_space(1))) void*)(p))
#define LDS_AS(p)    ((__attribute__((address_space(3))) void*)(p))
#define WAITV(n) asm volatile("s_waitcnt vmcnt(" #n ")" ::: "memory")
#define BARRIER() __builtin_amdgcn_s_barrier()

__device__ __forceinline__ unsigned short f2bf(float f) {
  unsigned int u = __builtin_bit_cast(unsigned int, f);
  u += 0x7fffu + ((u >> 16) & 1u);
  return (unsigned short)(u >> 16);
}
__device__ __forceinline__ float bf2f(unsigned short u) {
  unsigned int x = ((unsigned int)u) << 16;
  return __builtin_bit_cast(float, x);
}

// ---------------------------------------------------------------------------
// Transpose fp32 [K,N] -> bf16 [N,K]
__global__ __launch_bounds__(256) void transpose_to_bf16(
    const float* __restrict__ src, unsigned short* __restrict__ dst,
    int K, int N, int ntx) {
  __shared__ float tile[32][33];
  const int bx = blockIdx.x % ntx;
  const int by = blockIdx.x / ntx;
  const int tx = threadIdx.x & 31, ty = threadIdx.x >> 5;
  const int k0 = by * 32, n0 = bx * 32;
#pragma unroll
  for (int i = 0; i < 32; i += 8)
    tile[ty + i][tx] = src[(size_t)(k0 + ty + i) * N + n0 + tx];
  __syncthreads();
#pragma unroll
  for (int i = 0; i < 32; i += 8)
    dst[(size_t)(n0 + ty + i) * K + k0 + tx] = f2bf(tile[tx][ty + i]);
}

// fp32 -> bf16, 8 elements/thread
__global__ __launch_bounds__(256) void cvt_f32_bf16(
    const float* __restrict__ s, unsigned short* __restrict__ d) {
  size_t i = ((size_t)blockIdx.x * 256 + threadIdx.x) * 8;
  f32x4 v0 = *(const f32x4*)(s + i);
  f32x4 v1 = *(const f32x4*)(s + i + 4);
  union U8 { uint4v v; unsigned short us[8]; } o;
  o.us[0] = f2bf(v0.x); o.us[1] = f2bf(v0.y); o.us[2] = f2bf(v0.z); o.us[3] = f2bf(v0.w);
  o.us[4] = f2bf(v1.x); o.us[5] = f2bf(v1.y); o.us[6] = f2bf(v1.z); o.us[7] = f2bf(v1.w);
  *(uint4v*)(d + i) = o.v;
}

// combined bias concat: b1 = [bd_k|bd_v|bq] (3072), b2 = [bu_k|bu_v] (4096)
__global__ __launch_bounds__(256) void fill_bias(
    const float* __restrict__ bd_k, const float* __restrict__ bd_v,
    const float* __restrict__ bq, const float* __restrict__ bu_k,
    const float* __restrict__ bu_v, float* __restrict__ b1, float* __restrict__ b2) {
  int i = blockIdx.x * 256 + threadIdx.x;
  if (i < 512) b1[i] = bd_k[i];
  else if (i < 1024) b1[i] = bd_v[i - 512];
  else if (i < 3072) b1[i] = bq[i - 1024];
  else if (i < 5120) b2[i - 3072] = bu_k[i - 3072];
  else if (i < 7168) b2[i - 3072] = bu_v[i - 5120];
}

// ---------------------------------------------------------------------------
// 256x256x64 bf16 GEMM, 8 waves (2Mx4N), per-wave 128x64 = 4x2 tiles of 32x32.
// v_mfma_f32_32x32x16_bf16 (2382 TF ceiling vs 2075 for 16x16x32).
// R3-proven 2-phase loop: stage(T+1) -> vmcnt(8) -> barrier -> compute -> barrier.
// XOR-swizzled LDS via pre-swizzled global source (linear gload_lds dest).
// A/B frag: row/col = lane&31, k = (lane>>5)*8 + e (contiguous ds_read_b128).
// C/D frag: col = lane&31, row = (reg&3) + 8*(reg>>2) + 4*(lane>>5)  [m74/m101].
template <int OUT_BF16>
__global__ __launch_bounds__(512, 2) void gemm_bt(
    const unsigned short* __restrict__ A, int lda, int nsplit_col, int acol_off,
    const unsigned short* __restrict__ Bt, int ldb,
    const float* __restrict__ bias, void* __restrict__ Cp, int ldc,
    int K, int ntn) {
  __shared__ unsigned short lds[2][2][256 * 64];  // [dbuf][A|B][row*64+col]
  const int t = threadIdx.x;
  const int lane = t & 63, wave = t >> 6;

  // bijective XCD swizzle (grids here are multiples of 8)
  const int qx = gridDim.x >> 3;
  const int bid = (blockIdx.x & 7) * qx + (blockIdx.x >> 3);
  const int bm = (bid / ntn) * 256;
  const int bn = (bid % ntn) * 256;
  const unsigned short* Ab = A + (bn >= nsplit_col ? acol_off : 0);

  const int wr = wave >> 2, wc = wave & 3;
  const int l31 = lane & 31, khalf = lane >> 5;
  const int NT = K >> 6;

  f32x16 acc[4][2];
#pragma unroll
  for (int i = 0; i < 4; ++i)
#pragma unroll
    for (int j = 0; j < 2; ++j)
#pragma unroll
      for (int e = 0; e < 16; ++e) acc[i][j][e] = 0.f;

  // staging: one issue = 64 rows x 64 cols; thread t -> row t>>3, source
  // chunk inverse-XOR-swizzled so linear LDS dest + swizzled read match.
  const int trow = t >> 3;
  const int jsrc = (t & 7) ^ (trow & 7);
  const unsigned short* aptr = Ab + (size_t)(bm + trow) * lda + (jsrc << 3);
  const unsigned short* bptr = Bt + (size_t)(bn + trow) * ldb + (jsrc << 3);
  const int wbase = wave * 512;

  auto stage = [&](int kt, int buf) {
    const unsigned short* ak = aptr + kt * 64;
    const unsigned short* bk = bptr + kt * 64;
    unsigned short* la = &lds[buf][0][wbase];
    unsigned short* lb = &lds[buf][1][wbase];
#pragma unroll
    for (int c = 0; c < 4; ++c) {
      __builtin_amdgcn_global_load_lds(GLOBAL_AS(ak + (size_t)c * 64 * lda),
                                       LDS_AS(la + c * 4096), 16, 0, 0);
      __builtin_amdgcn_global_load_lds(GLOBAL_AS(bk + (size_t)c * 64 * ldb),
                                       LDS_AS(lb + c * 4096), 16, 0, 0);
    }
  };

  stage(0, 0);

  for (int kt = 0; kt < NT; ++kt) {
    const int cur = kt & 1;
    if (kt + 1 < NT) {
      stage(kt + 1, cur ^ 1);
      WAITV(8);   // tile kt resident; tile kt+1's 8 loads stay in flight
    } else {
      WAITV(0);
    }
    BARRIER();
    const unsigned short* la = lds[cur][0];
    const unsigned short* lb = lds[cur][1];
#pragma unroll
    for (int ks = 0; ks < 4; ++ks) {
      // logical 16B chunk (ks*2 + khalf), XOR-deswizzled by row&7 == l31&7
      const int coff = (((ks << 1) + khalf) ^ (l31 & 7)) << 3;
      short8v af[4], bf[2];
#pragma unroll
      for (int mt = 0; mt < 4; ++mt)
        af[mt] = *(const short8v*)&la[(wr * 128 + mt * 32 + l31) * 64 + coff];
#pragma unroll
      for (int nt = 0; nt < 2; ++nt)
        bf[nt] = *(const short8v*)&lb[(wc * 64 + nt * 32 + l31) * 64 + coff];
      __builtin_amdgcn_s_setprio(1);
#pragma unroll
      for (int mt = 0; mt < 4; ++mt)
#pragma unroll
        for (int nt = 0; nt < 2; ++nt)
          acc[mt][nt] = __builtin_amdgcn_mfma_f32_32x32x16_bf16(
              af[mt], bf[nt], acc[mt][nt], 0, 0, 0);
      __builtin_amdgcn_s_setprio(0);
    }
    BARRIER();
  }

#pragma unroll
  for (int nt = 0; nt < 2; ++nt) {
    const int col = bn + wc * 64 + nt * 32 + l31;
    const float bv = bias[col];
#pragma unroll
    for (int mt = 0; mt < 4; ++mt) {
      const int rbase = bm + wr * 128 + mt * 32 + 4 * khalf;
#pragma unroll
      for (int rg = 0; rg < 16; ++rg) {
        const int row = rbase + (rg & 3) + 8 * (rg >> 2);
        float v = acc[mt][nt][rg] + bv;
        if (OUT_BF16)
          ((unsigned short*)Cp)[(size_t)row * ldc + col] = f2bf(v);
        else
          ((float*)Cp)[(size_t)row * ldc + col] = v;
      }
    }
  }
}

// ---------------------------------------------------------------------------
// Per-token head-vs-head attention (16x16 per token), fp32 math.
__global__ __launch_bounds__(256) void attn_kernel(
    const unsigned short* __restrict__ out1, const unsigned short* __restrict__ kv,
    unsigned short* __restrict__ aout) {
  const int s = blockIdx.x;
  const int t = threadIdx.x;
  __shared__ float qs[16 * 132], ks2[16 * 132], vs[16 * 132];
  __shared__ float attn[256];
  const int h = t >> 4, d0 = (t & 15) * 8;

  union U8 { uint4v v; unsigned short us[8]; };
  U8 qv, kv8, vv;
  qv.v = *(const uint4v*)(out1 + (size_t)s * 3072 + 1024 + t * 8);
  kv8.v = *(const uint4v*)(kv + (size_t)s * 4096 + t * 8);
  vv.v = *(const uint4v*)(kv + (size_t)s * 4096 + 2048 + t * 8);
#pragma unroll
  for (int j = 0; j < 8; ++j) {
    qs[h * 132 + d0 + j] = bf2f(qv.us[j]);
    ks2[h * 132 + d0 + j] = bf2f(kv8.us[j]);
    vs[h * 132 + d0 + j] = bf2f(vv.us[j]);
  }
  __syncthreads();

  const int gg0 = t & 15;
  const f32x4* qrow = (const f32x4*)&qs[h * 132];
  const f32x4* krow = (const f32x4*)&ks2[gg0 * 132];
  float acc = 0.f;
#pragma unroll
  for (int dd = 0; dd < 32; ++dd) {
    f32x4 a4 = qrow[dd], b4 = krow[dd];
    acc += a4.x * b4.x + a4.y * b4.y + a4.z * b4.z + a4.w * b4.w;
  }
  acc *= 0.08838834764831845f;
  float mx = acc;
#pragma unroll
  for (int o = 8; o; o >>= 1) mx = fmaxf(mx, __shfl_xor(mx, o));
  float e = __expf(acc - mx);
  float sm = e;
#pragma unroll
  for (int o = 8; o; o >>= 1) sm += __shfl_xor(sm, o);
  attn[t] = e / sm;
  __syncthreads();

  f32x4 o0 = (f32x4){0.f, 0.f, 0.f, 0.f}, o1 = (f32x4){0.f, 0.f, 0.f, 0.f};
#pragma unroll
  for (int gg = 0; gg < 16; ++gg) {
    const float a = attn[(h << 4) + gg];
    f32x4 v0 = *(const f32x4*)&vs[gg * 132 + d0];
    f32x4 v1 = *(const f32x4*)&vs[gg * 132 + d0 + 4];
    o0 += v0 * a;
    o1 += v1 * a;
  }
  U8 ov;
  ov.us[0] = f2bf(o0.x); ov.us[1] = f2bf(o0.y); ov.us[2] = f2bf(o0.z); ov.us[3] = f2bf(o0.w);
  ov.us[4] = f2bf(o1.x); ov.us[5] = f2bf(o1.y); ov.us[6] = f2bf(o1.z); ov.us[7] = f2bf(o1.w);
  *(uint4v*)(aout + (size_t)s * 2048 + t * 8) = ov.v;
}

// ---------------------------------------------------------------------------
extern "C" void kernel_launch(void* const* d_in, const int* in_sizes, int n_in,
                              void* d_out, int out_size, void* d_ws, size_t ws_size,
                              hipStream_t stream) {
  (void)in_sizes; (void)n_in; (void)out_size; (void)ws_size;
  const float* x    = (const float*)d_in[0];
  const float* Wd_k = (const float*)d_in[1];
  const float* bd_k = (const float*)d_in[2];
  const float* Wu_k = (const float*)d_in[3];
  const float* bu_k = (const float*)d_in[4];
  const float* Wd_v = (const float*)d_in[5];
  const float* bd_v = (const float*)d_in[6];
  const float* Wu_v = (const float*)d_in[7];
  const float* bu_v = (const float*)d_in[8];
  const float* Wq   = (const float*)d_in[9];
  const float* bq   = (const float*)d_in[10];
  const float* Wo   = (const float*)d_in[11];
  const float* bo   = (const float*)d_in[12];

  char* ws = (char*)d_ws;
  unsigned short* w1t  = (unsigned short*)(ws);             // [3072][2048] bf16
  unsigned short* w2t  = (unsigned short*)(ws + 12582912);  // [4096][512]  bf16
  unsigned short* w3t  = (unsigned short*)(ws + 16777216);  // [2048][2048] bf16
  float*          b1   = (float*)(ws + 25165824);           // [3072]
  float*          b2   = (float*)(ws + 25178112);           // [4096]
  unsigned short* xb   = (unsigned short*)(ws + 25194496);  // [16384][2048] bf16
  unsigned short* out1 = (unsigned short*)(ws + 92303360);  // [16384][3072] bf16
  unsigned short* kvb  = (unsigned short*)(ws + 192966656); // [16384][4096] bf16
  unsigned short* attO = xb;  // reuse xb after GEMM1

  dim3 blk(256);

  transpose_to_bf16<<<dim3(16 * 64), blk, 0, stream>>>(Wd_k, w1t,               2048, 512, 16);
  transpose_to_bf16<<<dim3(16 * 64), blk, 0, stream>>>(Wd_v, w1t + 512 * 2048,  2048, 512, 16);
  transpose_to_bf16<<<dim3(64 * 64), blk, 0, stream>>>(Wq,   w1t + 1024 * 2048, 2048, 2048, 64);
  transpose_to_bf16<<<dim3(64 * 16), blk, 0, stream>>>(Wu_k, w2t,               512, 2048, 64);
  transpose_to_bf16<<<dim3(64 * 16), blk, 0, stream>>>(Wu_v, w2t + 2048 * 512,  512, 2048, 64);
  transpose_to_bf16<<<dim3(64 * 64), blk, 0, stream>>>(Wo,   w3t,               2048, 2048, 64);

  fill_bias<<<dim3(28), blk, 0, stream>>>(bd_k, bd_v, bq, bu_k, bu_v, b1, b2);

  cvt_f32_bf16<<<dim3(16384), blk, 0, stream>>>(x, xb);

  // GEMM1: [16384,2048]@[2048,3072] -> out1 (cache_k|cache_v|q)
  gemm_bt<1><<<dim3(64 * 12), dim3(512), 0, stream>>>(
      xb, 2048, 1 << 30, 0, w1t, 2048, b1, out1, 3072, 2048, 12);

  // GEMM2 fused: k|v = [cache_k|cache_v]@blockdiag(Wu_k,Wu_v) -> kvb
  gemm_bt<1><<<dim3(64 * 16), dim3(512), 0, stream>>>(
      out1, 3072, 2048, 512, w2t, 512, b2, kvb, 4096, 512, 16);

  // per-token attention
  attn_kernel<<<dim3(16384), blk, 0, stream>>>(out1, kvb, attO);

  // GEMM3: attO@Wo + bo -> d_out fp32
  gemm_bt<0><<<dim3(64 * 8), dim3(512), 0, stream>>>(
      attO, 2048, 1 << 30, 0, w3t, 2048, bo, (float*)d_out, 2048, 2048, 8);
}

// Round 7
// 579.737 us; speedup vs baseline: 1.0710x; 1.0503x over previous
//
#include <hip/hip_runtime.h>

typedef __attribute__((ext_vector_type(8))) short short8v;
typedef __attribute__((ext_vector_type(4))) float f32x4;
typedef __attribute__((ext_vector_type(4))) unsigned int uint4v;

#define GLOBAL_AS(p) ((const __attribute__((address_space(1))) void*)(p))
#define LDS_AS(p)    ((__attribute__((address_space(3))) void*)(p))
#define WAITV(n) asm volatile("s_waitcnt vmcnt(" #n ")" ::: "memory")
#define LGKM0()  asm volatile("s_waitcnt lgkmcnt(0)" ::: "memory")
#define BARRIER() __builtin_amdgcn_s_barrier()
#define SCHED0() __builtin_amdgcn_sched_barrier(0)

__device__ __forceinline__ unsigned short f2bf(float f) {
  unsigned int u = __builtin_bit_cast(unsigned int, f);
  u += 0x7fffu + ((u >> 16) & 1u);
  return (unsigned short)(u >> 16);
}
__device__ __forceinline__ float bf2f(unsigned short u) {
  unsigned int x = ((unsigned int)u) << 16;
  return __builtin_bit_cast(float, x);
}

// ---------------------------------------------------------------------------
// Transpose fp32 [K,N] -> bf16 [N,K]
__global__ __launch_bounds__(256) void transpose_to_bf16(
    const float* __restrict__ src, unsigned short* __restrict__ dst,
    int K, int N, int ntx) {
  __shared__ float tile[32][33];
  const int bx = blockIdx.x % ntx;
  const int by = blockIdx.x / ntx;
  const int tx = threadIdx.x & 31, ty = threadIdx.x >> 5;
  const int k0 = by * 32, n0 = bx * 32;
#pragma unroll
  for (int i = 0; i < 32; i += 8)
    tile[ty + i][tx] = src[(size_t)(k0 + ty + i) * N + n0 + tx];
  __syncthreads();
#pragma unroll
  for (int i = 0; i < 32; i += 8)
    dst[(size_t)(n0 + ty + i) * K + k0 + tx] = f2bf(tile[tx][ty + i]);
}

// fp32 -> bf16, 8 elements/thread
__global__ __launch_bounds__(256) void cvt_f32_bf16(
    const float* __restrict__ s, unsigned short* __restrict__ d) {
  size_t i = ((size_t)blockIdx.x * 256 + threadIdx.x) * 8;
  f32x4 v0 = *(const f32x4*)(s + i);
  f32x4 v1 = *(const f32x4*)(s + i + 4);
  union U8 { uint4v v; unsigned short us[8]; } o;
  o.us[0] = f2bf(v0.x); o.us[1] = f2bf(v0.y); o.us[2] = f2bf(v0.z); o.us[3] = f2bf(v0.w);
  o.us[4] = f2bf(v1.x); o.us[5] = f2bf(v1.y); o.us[6] = f2bf(v1.z); o.us[7] = f2bf(v1.w);
  *(uint4v*)(d + i) = o.v;
}

// combined bias concat: b1 = [bd_k|bd_v|bq] (3072), b2 = [bu_k|bu_v] (4096)
__global__ __launch_bounds__(256) void fill_bias(
    const float* __restrict__ bd_k, const float* __restrict__ bd_v,
    const float* __restrict__ bq, const float* __restrict__ bu_k,
    const float* __restrict__ bu_v, float* __restrict__ b1, float* __restrict__ b2) {
  int i = blockIdx.x * 256 + threadIdx.x;
  if (i < 512) b1[i] = bd_k[i];
  else if (i < 1024) b1[i] = bd_v[i - 512];
  else if (i < 3072) b1[i] = bq[i - 1024];
  else if (i < 5120) b2[i - 3072] = bu_k[i - 3072];
  else if (i < 7168) b2[i - 3072] = bu_v[i - 5120];
}

// ---------------------------------------------------------------------------
// 256x256x64 bf16 GEMM, 8 waves (2Mx4N), per-wave 128x64, 16x16x32 MFMA.
// 4 phases/tile: p1(miLO,ks0) p2(miLO,ks1) p3(miHI,ks0) p4(miHI,ks1).
// B frags read in p1/p2, HELD IN REGS for p3/p4 -> B LDS dead after p2.
// Phase = vmcnt? -> barrier -> ds_reads -> stage -> lgkm0 -> sched0 -> 16 MFMA.
// Dead-slot staging (>=5-phase lead, covers ~900cy HBM latency):
//   p1: A-odd(T+1)->nxt   (slots dead since T-1.p4; consumed T+1.p3)
//   p3: B(T+2)->cur       (B slots dead after p2; consumed T+2.p1)
//   p4: A-even(T+2)->cur  (dead after p2; consumed T+2.p1)
// Waits (per-wave bookkeeping): p1: vmcnt(8) [last tile: 2];
//                               p3: vmcnt(8) [last tile: 0].
template <int OUT_BF16>
__global__ __launch_bounds__(512, 2) void gemm_bt(
    const unsigned short* __restrict__ A, int lda, int nsplit_col, int acol_off,
    const unsigned short* __restrict__ Bt, int ldb,
    const float* __restrict__ bias, void* __restrict__ Cp, int ldc,
    int K, int ntn) {
  __shared__ unsigned short lds[2][2][256 * 64];  // [dbuf][A|B][row*64+col]
  const int t = threadIdx.x;
  const int lane = t & 63, wave = t >> 6;

  // bijective XCD swizzle (grids here are multiples of 8)
  const int qx = gridDim.x >> 3;
  const int bid = (blockIdx.x & 7) * qx + (blockIdx.x >> 3);
  const int bm = (bid / ntn) * 256;
  const int bn = (bid % ntn) * 256;
  const unsigned short* Ab = A + (bn >= nsplit_col ? acol_off : 0);

  const int wr = wave >> 2, wc = wave & 3;
  const int g = lane >> 4, r = lane & 15;
  const int swz = r & 7;
  const int NT = K >> 6;

  f32x4 acc[8][4];
#pragma unroll
  for (int i = 0; i < 8; ++i)
#pragma unroll
    for (int j = 0; j < 4; ++j) acc[i][j] = (f32x4){0.f, 0.f, 0.f, 0.f};

  // staging: one issue = 64 rows x 64 cols; thread t -> row t>>3, source
  // chunk inverse-XOR-swizzled so linear LDS dest + swizzled read match.
  const int trow = t >> 3;
  const int jsrc = (t & 7) ^ (trow & 7);
  const unsigned short* aptr = Ab + (size_t)(bm + trow) * lda + (jsrc << 3);
  const unsigned short* bptr = Bt + (size_t)(bn + trow) * ldb + (jsrc << 3);
  const int wbase = wave * 512;

  auto stageA = [&](int kt, int buf, int q64) {
    __builtin_amdgcn_global_load_lds(
        GLOBAL_AS(aptr + (size_t)(q64 * 64) * lda + kt * 64),
        LDS_AS(&lds[buf][0][q64 * 4096 + wbase]), 16, 0, 0);
  };
  auto stageB = [&](int kt, int buf, int q64) {
    __builtin_amdgcn_global_load_lds(
        GLOBAL_AS(bptr + (size_t)(q64 * 64) * ldb + kt * 64),
        LDS_AS(&lds[buf][1][q64 * 4096 + wbase]), 16, 0, 0);
  };

  auto readA = [&](const unsigned short* la, int miH, int ks, short8v (&af)[4]) {
    const int c16 = (((ks << 2) + g) ^ swz) << 3;
#pragma unroll
    for (int mi = 0; mi < 4; ++mi)
      af[mi] = *(const short8v*)&la[(wr * 128 + miH * 64 + mi * 16 + r) * 64 + c16];
  };
  auto readB = [&](const unsigned short* lb, int ks, short8v (&bf)[4]) {
    const int c16 = (((ks << 2) + g) ^ swz) << 3;
#pragma unroll
    for (int ni = 0; ni < 4; ++ni)
      bf[ni] = *(const short8v*)&lb[(wc * 64 + ni * 16 + r) * 64 + c16];
  };
  auto mfma8 = [&](int miH, short8v (&af)[4], short8v (&bf)[4]) {
    __builtin_amdgcn_s_setprio(1);
#pragma unroll
    for (int mi = 0; mi < 4; ++mi)
#pragma unroll
      for (int ni = 0; ni < 4; ++ni)
        acc[miH * 4 + mi][ni] = __builtin_amdgcn_mfma_f32_16x16x32_bf16(
            af[mi], bf[ni], acc[miH * 4 + mi][ni], 0, 0, 0);
    __builtin_amdgcn_s_setprio(0);
  };

  // prologue — order mirrors steady state for vmcnt bookkeeping:
  // [B(0) x4, Aev(0) x2] = "T-2.p3/p4"; [Aodd(0) x2] = "T-1.p1";
  // [B(1) x4, Aev(1) x2] = "T-1.p3/p4".
  stageB(0, 0, 0); stageB(0, 0, 1); stageB(0, 0, 2); stageB(0, 0, 3);
  stageA(0, 0, 0); stageA(0, 0, 2);
  stageA(0, 0, 1); stageA(0, 0, 3);
  if (NT > 1) {
    stageB(1, 1, 0); stageB(1, 1, 1); stageB(1, 1, 2); stageB(1, 1, 3);
    stageA(1, 1, 0); stageA(1, 1, 2);
  }

  for (int T = 0; T < NT; ++T) {
    const int cur = T & 1, nxt = cur ^ 1;
    const unsigned short* la = lds[cur][0];
    const unsigned short* lb = lds[cur][1];
    const bool s1 = (T + 1 < NT), s2 = (T + 2 < NT);
    short8v af[4], bf0[4], bf1[4];

    // ---- p1: miLO x ks0 | stage A-odd(T+1) -> nxt
    if (s1) { WAITV(8); } else { WAITV(2); }
    BARRIER(); SCHED0();
    readA(la, 0, 0, af);
    readB(lb, 0, bf0);
    if (s1) { stageA(T + 1, nxt, 1); stageA(T + 1, nxt, 3); }
    LGKM0(); SCHED0();
    mfma8(0, af, bf0);

    // ---- p2: miLO x ks1
    BARRIER(); SCHED0();
    readA(la, 0, 1, af);
    readB(lb, 1, bf1);
    LGKM0(); SCHED0();
    mfma8(0, af, bf1);

    // ---- p3: miHI x ks0 | stage B(T+2) -> cur (B slots dead after p2)
    if (s1) { WAITV(8); } else { WAITV(0); }
    BARRIER(); SCHED0();
    readA(la, 1, 0, af);
    if (s2) { stageB(T + 2, cur, 0); stageB(T + 2, cur, 1);
              stageB(T + 2, cur, 2); stageB(T + 2, cur, 3); }
    LGKM0(); SCHED0();
    mfma8(1, af, bf0);

    // ---- p4: miHI x ks1 | stage A-even(T+2) -> cur
    BARRIER(); SCHED0();
    readA(la, 1, 1, af);
    if (s2) { stageA(T + 2, cur, 0); stageA(T + 2, cur, 2); }
    LGKM0(); SCHED0();
    mfma8(1, af, bf1);
  }

#pragma unroll
  for (int ni = 0; ni < 4; ++ni) {
    const int col = bn + wc * 64 + ni * 16 + r;
    const float bv = bias[col];
#pragma unroll
    for (int mi = 0; mi < 8; ++mi) {
      const int row0 = bm + wr * 128 + mi * 16 + (g << 2);
#pragma unroll
      for (int j = 0; j < 4; ++j) {
        float v = acc[mi][ni][j] + bv;
        if (OUT_BF16)
          ((unsigned short*)Cp)[(size_t)(row0 + j) * ldc + col] = f2bf(v);
        else
          ((float*)Cp)[(size_t)(row0 + j) * ldc + col] = v;
      }
    }
  }
}

// ---------------------------------------------------------------------------
// Per-token head-vs-head attention (16x16 per token), fp32 math.
__global__ __launch_bounds__(256) void attn_kernel(
    const unsigned short* __restrict__ out1, const unsigned short* __restrict__ kv,
    unsigned short* __restrict__ aout) {
  const int s = blockIdx.x;
  const int t = threadIdx.x;
  __shared__ float qs[16 * 132], ks2[16 * 132], vs[16 * 132];
  __shared__ float attn[256];
  const int h = t >> 4, d0 = (t & 15) * 8;

  union U8 { uint4v v; unsigned short us[8]; };
  U8 qv, kv8, vv;
  qv.v = *(const uint4v*)(out1 + (size_t)s * 3072 + 1024 + t * 8);
  kv8.v = *(const uint4v*)(kv + (size_t)s * 4096 + t * 8);
  vv.v = *(const uint4v*)(kv + (size_t)s * 4096 + 2048 + t * 8);
#pragma unroll
  for (int j = 0; j < 8; ++j) {
    qs[h * 132 + d0 + j] = bf2f(qv.us[j]);
    ks2[h * 132 + d0 + j] = bf2f(kv8.us[j]);
    vs[h * 132 + d0 + j] = bf2f(vv.us[j]);
  }
  __syncthreads();

  const int gg0 = t & 15;
  const f32x4* qrow = (const f32x4*)&qs[h * 132];
  const f32x4* krow = (const f32x4*)&ks2[gg0 * 132];
  float acc = 0.f;
#pragma unroll
  for (int dd = 0; dd < 32; ++dd) {
    f32x4 a4 = qrow[dd], b4 = krow[dd];
    acc += a4.x * b4.x + a4.y * b4.y + a4.z * b4.z + a4.w * b4.w;
  }
  acc *= 0.08838834764831845f;
  float mx = acc;
#pragma unroll
  for (int o = 8; o; o >>= 1) mx = fmaxf(mx, __shfl_xor(mx, o));
  float e = __expf(acc - mx);
  float sm = e;
#pragma unroll
  for (int o = 8; o; o >>= 1) sm += __shfl_xor(sm, o);
  attn[t] = e / sm;
  __syncthreads();

  f32x4 o0 = (f32x4){0.f, 0.f, 0.f, 0.f}, o1 = (f32x4){0.f, 0.f, 0.f, 0.f};
#pragma unroll
  for (int gg = 0; gg < 16; ++gg) {
    const float a = attn[(h << 4) + gg];
    f32x4 v0 = *(const f32x4*)&vs[gg * 132 + d0];
    f32x4 v1 = *(const f32x4*)&vs[gg * 132 + d0 + 4];
    o0 += v0 * a;
    o1 += v1 * a;
  }
  U8 ov;
  ov.us[0] = f2bf(o0.x); ov.us[1] = f2bf(o0.y); ov.us[2] = f2bf(o0.z); ov.us[3] = f2bf(o0.w);
  ov.us[4] = f2bf(o1.x); ov.us[5] = f2bf(o1.y); ov.us[6] = f2bf(o1.z); ov.us[7] = f2bf(o1.w);
  *(uint4v*)(aout + (size_t)s * 2048 + t * 8) = ov.v;
}

// ---------------------------------------------------------------------------
extern "C" void kernel_launch(void* const* d_in, const int* in_sizes, int n_in,
                              void* d_out, int out_size, void* d_ws, size_t ws_size,
                              hipStream_t stream) {
  (void)in_sizes; (void)n_in; (void)out_size; (void)ws_size;
  const float* x    = (const float*)d_in[0];
  const float* Wd_k = (const float*)d_in[1];
  const float* bd_k = (const float*)d_in[2];
  const float* Wu_k = (const float*)d_in[3];
  const float* bu_k = (const float*)d_in[4];
  const float* Wd_v = (const float*)d_in[5];
  const float* bd_v = (const float*)d_in[6];
  const float* Wu_v = (const float*)d_in[7];
  const float* bu_v = (const float*)d_in[8];
  const float* Wq   = (const float*)d_in[9];
  const float* bq   = (const float*)d_in[10];
  const float* Wo   = (const float*)d_in[11];
  const float* bo   = (const float*)d_in[12];

  char* ws = (char*)d_ws;
  unsigned short* w1t  = (unsigned short*)(ws);             // [3072][2048] bf16
  unsigned short* w2t  = (unsigned short*)(ws + 12582912);  // [4096][512]  bf16
  unsigned short* w3t  = (unsigned short*)(ws + 16777216);  // [2048][2048] bf16
  float*          b1   = (float*)(ws + 25165824);           // [3072]
  float*          b2   = (float*)(ws + 25178112);           // [4096]
  unsigned short* xb   = (unsigned short*)(ws + 25194496);  // [16384][2048] bf16
  unsigned short* out1 = (unsigned short*)(ws + 92303360);  // [16384][3072] bf16
  unsigned short* kvb  = (unsigned short*)(ws + 192966656); // [16384][4096] bf16
  unsigned short* attO = xb;  // reuse xb after GEMM1

  dim3 blk(256);

  transpose_to_bf16<<<dim3(16 * 64), blk, 0, stream>>>(Wd_k, w1t,               2048, 512, 16);
  transpose_to_bf16<<<dim3(16 * 64), blk, 0, stream>>>(Wd_v, w1t + 512 * 2048,  2048, 512, 16);
  transpose_to_bf16<<<dim3(64 * 64), blk, 0, stream>>>(Wq,   w1t + 1024 * 2048, 2048, 2048, 64);
  transpose_to_bf16<<<dim3(64 * 16), blk, 0, stream>>>(Wu_k, w2t,               512, 2048, 64);
  transpose_to_bf16<<<dim3(64 * 16), blk, 0, stream>>>(Wu_v, w2t + 2048 * 512,  512, 2048, 64);
  transpose_to_bf16<<<dim3(64 * 64), blk, 0, stream>>>(Wo,   w3t,               2048, 2048, 64);

  fill_bias<<<dim3(28), blk, 0, stream>>>(bd_k, bd_v, bq, bu_k, bu_v, b1, b2);

  cvt_f32_bf16<<<dim3(16384), blk, 0, stream>>>(x, xb);

  // GEMM1: [16384,2048]@[2048,3072] -> out1 (cache_k|cache_v|q)
  gemm_bt<1><<<dim3(64 * 12), dim3(512), 0, stream>>>(
      xb, 2048, 1 << 30, 0, w1t, 2048, b1, out1, 3072, 2048, 12);

  // GEMM2 fused: k|v = [cache_k|cache_v]@blockdiag(Wu_k,Wu_v) -> kvb
  gemm_bt<1><<<dim3(64 * 16), dim3(512), 0, stream>>>(
      out1, 3072, 2048, 512, w2t, 512, b2, kvb, 4096, 512, 16);

  // per-token attention
  attn_kernel<<<dim3(16384), blk, 0, stream>>>(out1, kvb, attO);

  // GEMM3: attO@Wo + bo -> d_out fp32
  gemm_bt<0><<<dim3(64 * 8), dim3(512), 0, stream>>>(
      attO, 2048, 1 << 30, 0, w3t, 2048, bo, (float*)d_out, 2048, 2048, 8);
}